// Round 3
// baseline (691.459 us; speedup 1.0000x reference)
//
#include <hip/hip_runtime.h>
#include <math.h>

// Problem constants (fixed by reference)
#define S_LEN   2048
#define HDIM    1024
#define NHEADS  16
#define DHEAD   64
#define BATCH   2
#define MROWS   (BATCH * S_LEN)   // 4096
#define STRIDE  4
#define LOCAL   8

typedef __attribute__((ext_vector_type(8))) short s16x8;   // 8 bf16 (4 VGPRs)
typedef __attribute__((ext_vector_type(4))) float f32x4;

// ---- fp32 -> bf16 round-to-nearest-even, and back --------------------------
__device__ __forceinline__ unsigned short bf16_rn(float x) {
    unsigned u = __float_as_uint(x);
    unsigned r = (u + 0x7FFFu + ((u >> 16) & 1u)) >> 16;
    return (unsigned short)r;
}
__device__ __forceinline__ float bf16_f(unsigned short h) {
    return __uint_as_float(((unsigned)h) << 16);
}

// ---- async global->LDS, 16B per lane (dest = wave base + lane*16) ----------
__device__ __forceinline__ void gll16(const void* g, void* l) {
    __builtin_amdgcn_global_load_lds(
        (const __attribute__((address_space(1))) void*)g,
        (__attribute__((address_space(3))) void*)l, 16, 0, 0);
}

// ---------------------------------------------------------------------------
// Prep 1: elementwise fp32 -> (bf16 hi, bf16 lo) split. 4 elems/thread.
// ---------------------------------------------------------------------------
__global__ __launch_bounds__(256)
void split_kernel(const float* __restrict__ src, unsigned short* __restrict__ hi,
                  unsigned short* __restrict__ lo, int n4)
{
    const int i = blockIdx.x * 256 + threadIdx.x;
    if (i >= n4) return;
    const float4 v = reinterpret_cast<const float4*>(src)[i];
    const float vv[4] = {v.x, v.y, v.z, v.w};
    unsigned short hh[4], ll[4];
#pragma unroll
    for (int j = 0; j < 4; j++) {
        hh[j] = bf16_rn(vv[j]);
        ll[j] = bf16_rn(vv[j] - bf16_f(hh[j]));
    }
    reinterpret_cast<ushort4*>(hi)[i] = make_ushort4(hh[0], hh[1], hh[2], hh[3]);
    reinterpret_cast<ushort4*>(lo)[i] = make_ushort4(ll[0], ll[1], ll[2], ll[3]);
}

// ---------------------------------------------------------------------------
// Prep 2: weight [K][N] fp32 -> transposed bf16 hi/lo [N][K], 32x32 LDS tiles.
// ---------------------------------------------------------------------------
__global__ __launch_bounds__(256)
void wsplit_kernel(const float* __restrict__ W,
                   unsigned short* __restrict__ hiT, unsigned short* __restrict__ loT)
{
    __shared__ unsigned short his[32][33];
    __shared__ unsigned short los[32][33];
    const int t  = threadIdx.x;
    const int kb = blockIdx.x * 32;
    const int nb = blockIdx.y * 32;
    {
        const int row = t >> 3;          // k within tile
        const int c4  = (t & 7) * 4;     // n within tile
        const float4 v = *reinterpret_cast<const float4*>(
            &W[(size_t)(kb + row) * HDIM + nb + c4]);
        const float vv[4] = {v.x, v.y, v.z, v.w};
#pragma unroll
        for (int j = 0; j < 4; j++) {
            const unsigned short h = bf16_rn(vv[j]);
            his[row][c4 + j] = h;
            los[row][c4 + j] = bf16_rn(vv[j] - bf16_f(h));
        }
    }
    __syncthreads();
    {
        const int n  = t >> 3;
        const int k4 = (t & 7) * 4;
        const ushort4 h = make_ushort4(his[k4][n], his[k4+1][n], his[k4+2][n], his[k4+3][n]);
        const ushort4 l = make_ushort4(los[k4][n], los[k4+1][n], los[k4+2][n], los[k4+3][n]);
        *reinterpret_cast<ushort4*>(&hiT[(size_t)(nb + n) * HDIM + kb + k4]) = h;
        *reinterpret_cast<ushort4*>(&loT[(size_t)(nb + n) * HDIM + kb + k4]) = l;
    }
}

// ---------------------------------------------------------------------------
// MFMA GEMM with 3-term bf16 split: C = Ahi@Whi + Ahi@Wlo + Alo@Whi.
// A: [4096][1024] bf16 (hi/lo). Weights TRANSPOSED [N][K] bf16, packed as
// [W0_hi|W0_lo|W1_hi|W1_lo|...] selected by blockIdx.z; output C + z*M*N.
// Virtual K = 3*1024, BK=64. Tile 128x128, 4 waves (2x2), 4x4 frags/wave.
// LDS double-buffered; global_load_lds w/ pre-swizzled source (T2 swizzle).
// mode 0: scatter to [B,NH,S,D]; sigmoid(*sig)/8 scale applied iff z==0.
// mode 1: flat [M][N] + bias.
// ---------------------------------------------------------------------------
__global__ __launch_bounds__(256)
void gemm_mfma(const unsigned short* __restrict__ Ahi, const unsigned short* __restrict__ Alo,
               const unsigned short* __restrict__ Wbase,
               float* __restrict__ Cbase, const float* __restrict__ bias,
               const float* __restrict__ sig_ptr, int mode)
{
    __shared__ unsigned short As[2][128 * 64];
    __shared__ unsigned short Bs[2][128 * 64];

    const int z = blockIdx.z;
    const unsigned short* __restrict__ WhiT = Wbase + (size_t)z * 2097152;
    const unsigned short* __restrict__ WloT = WhiT + 1048576;
    float* __restrict__ C = Cbase + (size_t)z * ((size_t)MROWS * HDIM);

    const int tid  = threadIdx.x;
    const int lane = tid & 63;
    const int w    = tid >> 6;
    const int wr   = w >> 1;      // wave row (0..1) -> 64 rows each
    const int wc   = w & 1;      // wave col (0..1) -> 64 cols each
    const int row_base = blockIdx.y * 128;
    const int col_base = blockIdx.x * 128;

    f32x4 acc[4][4] = {};

    // stage one 128x64 A-tile + 128x64 B-tile (bf16) into LDS buffer b.
    // LDS dest is linear in chunk id (global_load_lds constraint); the
    // global source is pre-swizzled so swizzled reads land correctly.
    auto stage = [&](int b, const unsigned short* Ap, const unsigned short* Bp, int k0) {
#pragma unroll
        for (int r = 0; r < 4; ++r) {
            const int c    = tid + r * 256;      // chunk id 0..1023
            const int row  = c >> 3;             // tile row 0..127
            const int c7   = c & 7;              // 16B chunk within 128B row
            const int goff = ((c7 * 16) ^ ((row & 7) << 4)) >> 1;  // bf16 elems
            gll16(Ap + (size_t)(row_base + row) * HDIM + k0 + goff, &As[b][c * 8]);
            gll16(Bp + (size_t)(col_base + row) * HDIM + k0 + goff, &Bs[b][c * 8]);
        }
    };

    auto compute = [&](int b) {
#pragma unroll
        for (int kk = 0; kk < 2; ++kk) {
            // byte col offset within 128B row, then XOR-swizzle by row&7
            const int sofs = (kk * 64 + ((lane >> 4) << 4)) ^ ((lane & 7) << 4);
            s16x8 af[4], bfr[4];
#pragma unroll
            for (int mi = 0; mi < 4; ++mi) {
                const int row = wr * 64 + mi * 16 + (lane & 15);
                af[mi] = *reinterpret_cast<const s16x8*>(
                    reinterpret_cast<const char*>(&As[b][row * 64]) + sofs);
            }
#pragma unroll
            for (int ni = 0; ni < 4; ++ni) {
                const int row = wc * 64 + ni * 16 + (lane & 15);
                bfr[ni] = *reinterpret_cast<const s16x8*>(
                    reinterpret_cast<const char*>(&Bs[b][row * 64]) + sofs);
            }
#pragma unroll
            for (int mi = 0; mi < 4; ++mi)
#pragma unroll
                for (int ni = 0; ni < 4; ++ni)
                    acc[mi][ni] = __builtin_amdgcn_mfma_f32_16x16x32_bf16(
                        af[mi], bfr[ni], acc[mi][ni], 0, 0, 0);
        }
    };

    // ---- 2-phase pipelined K-loop: 48 virtual steps (3 variants x 16) ----
    stage(0, Ahi, WhiT, 0);
    __syncthreads();
    int buf = 0;
#pragma unroll 1
    for (int kt = 0; kt < 48; ++kt) {
        if (kt + 1 < 48) {
            const int nx = kt + 1;
            const int v  = nx >> 4;
            const int k0 = (nx & 15) * 64;
            const unsigned short* Ap = (v == 2) ? Alo  : Ahi;
            const unsigned short* Bp = (v == 1) ? WloT : WhiT;
            stage(buf ^ 1, Ap, Bp, k0);
        }
        compute(buf);
        __syncthreads();          // drains prefetch vmcnt + frees buf
        buf ^= 1;
    }

    // ---- epilogue ----
    float scale = 1.0f;
    if (mode == 0 && sig_ptr != nullptr && z == 0) {
        const float u = *sig_ptr;
        scale = (1.0f / (1.0f + __expf(-u))) * 0.125f;  // sigmoid(phi)/sqrt(D)
    }
#pragma unroll
    for (int mi = 0; mi < 4; ++mi) {
#pragma unroll
        for (int ni = 0; ni < 4; ++ni) {
            const int gr0 = row_base + wr * 64 + mi * 16 + ((lane >> 4) << 2);
            const int gc  = col_base + wc * 64 + ni * 16 + (lane & 15);
            if (mode == 0) {
                const int h = gc >> 6, d = gc & 63;
#pragma unroll
                for (int r = 0; r < 4; ++r) {
                    const int gr = gr0 + r;
                    const int bb = gr >> 11, s = gr & (S_LEN - 1);
                    C[((size_t)((bb * NHEADS + h) * S_LEN + s)) * DHEAD + d] =
                        acc[mi][ni][r] * scale;
                }
            } else {
                const float bv = bias[gc];
#pragma unroll
                for (int r = 0; r < 4; ++r)
                    C[(size_t)(gr0 + r) * HDIM + gc] = acc[mi][ni][r] + bv;
            }
        }
    }
}

// ---------------------------------------------------------------------------
// Sparse ("strided") flash attention, fp32, KEY-SPLIT for occupancy.
// Block = 256 threads = 4 waves; 64 q-rows/block (row = tid&63).
// Wave kg (tid>>6) handles strided keys [kg*128, kg*128+128) and the band
// offsets dj = kg-8+4t. No LDS staging, no barriers in the main loop:
// all 64 lanes broadcast-read the same K/V row from L1/L2; latency hidden
// by 3-4 waves/SIMD of TLP. Partial (m,l,o[64]) merged via 2-round LDS tree.
// Output written as bf16 hi/lo split (feeds the final MFMA GEMM).
// ---------------------------------------------------------------------------
#define QR 64   // q rows per block

__global__ __launch_bounds__(256)
void attn_kernel(const float* __restrict__ Q, const float* __restrict__ K,
                 const float* __restrict__ V,
                 unsigned short* __restrict__ Ohi, unsigned short* __restrict__ Olo)
{
    __shared__ float mb[2][QR][67];   // [0]=m, [1]=l, [2+d]=o[d]; stride 67 -> conflict-free

    const int tid = threadIdx.x;
    const int row = tid & 63;
    const int kg  = tid >> 6;         // key group 0..3
    const int bx  = blockIdx.x;
    const int qt  = bx & 31;          // 32 q-tiles of 64 rows
    const int h   = (bx >> 5) & 15;
    const int b   = bx >> 9;
    const int s   = qt * QR + row;

    const float* __restrict__ Kbh = K + (size_t)((b * NHEADS + h) * S_LEN) * DHEAD;
    const float* __restrict__ Vbh = V + (size_t)((b * NHEADS + h) * S_LEN) * DHEAD;
    const float* __restrict__ qrow =
        Q + ((size_t)((b * NHEADS + h) * S_LEN + s)) * DHEAD;

    float q[DHEAD];
#pragma unroll
    for (int d4 = 0; d4 < DHEAD / 4; d4++) {
        const float4 v = *reinterpret_cast<const float4*>(&qrow[d4 * 4]);
        q[d4*4+0] = v.x; q[d4*4+1] = v.y; q[d4*4+2] = v.z; q[d4*4+3] = v.w;
    }

    float o[DHEAD];
#pragma unroll
    for (int d = 0; d < DHEAD; d++) o[d] = 0.0f;
    float m = -1e30f;
    float l = 0.0f;

    auto process_key = [&](const float* __restrict__ krow,
                           const float* __restrict__ vrow) {
        float s0 = 0.f, s1 = 0.f, s2 = 0.f, s3 = 0.f;
#pragma unroll
        for (int d = 0; d < DHEAD; d += 4) {
            const float4 kv = *reinterpret_cast<const float4*>(&krow[d]);
            s0 = fmaf(q[d+0], kv.x, s0);
            s1 = fmaf(q[d+1], kv.y, s1);
            s2 = fmaf(q[d+2], kv.z, s2);
            s3 = fmaf(q[d+3], kv.w, s3);
        }
        const float sc = (s0 + s1) + (s2 + s3);
        if (sc > m + 8.0f) {             // defer-max: rare rescale
            const float f = __expf(m - sc);
            m = sc;
            l *= f;
#pragma unroll
            for (int d = 0; d < DHEAD; d++) o[d] *= f;
        }
        const float p = __expf(sc - m);  // bounded by e^8
        l += p;
#pragma unroll
        for (int d = 0; d < DHEAD; d += 4) {
            const float4 vv = *reinterpret_cast<const float4*>(&vrow[d]);
            o[d+0] = fmaf(p, vv.x, o[d+0]);
            o[d+1] = fmaf(p, vv.y, o[d+1]);
            o[d+2] = fmaf(p, vv.z, o[d+2]);
            o[d+3] = fmaf(p, vv.w, o[d+3]);
        }
    };

    // ---- phase 1: this wave's 128 strided keys (j = 4*jj) ----
    const int jj0 = kg * 128;
#pragma unroll 2
    for (int kk = 0; kk < 128; ++kk) {
        const size_t off = (size_t)((jj0 + kk) * STRIDE) * DHEAD;
        process_key(Kbh + off, Vbh + off);
    }

    // ---- phase 2: this wave's slice of the local band (j%4 != 0) ----
#pragma unroll
    for (int t = 0; t < 5; ++t) {
        const int dj = kg - LOCAL + 4 * t;
        if (dj > LOCAL) continue;        // only kg==0 reaches t==4
        const int j = s + dj;
        if (j < 0 || j >= S_LEN || ((j & 3) == 0)) continue;
        const size_t off = (size_t)j * DHEAD;
        process_key(Kbh + off, Vbh + off);
    }

    // ---- 2-round LDS tree merge of 4 wave-partials ----
    auto store_partial = [&](int bufidx) {
        mb[bufidx][row][0] = m;
        mb[bufidx][row][1] = l;
#pragma unroll
        for (int d = 0; d < DHEAD; d++) mb[bufidx][row][2 + d] = o[d];
    };
    auto merge_partial = [&](int bufidx) {
        const float m2 = mb[bufidx][row][0];
        const float l2 = mb[bufidx][row][1];
        const float M  = fmaxf(m, m2);
        const float f1 = __expf(m - M);
        const float f2 = __expf(m2 - M);
        l = l * f1 + l2 * f2;
#pragma unroll
        for (int d = 0; d < DHEAD; d++)
            o[d] = o[d] * f1 + mb[bufidx][row][2 + d] * f2;
        m = M;
    };

    if (kg >= 2) store_partial(kg - 2);      // waves 2,3 -> buf 0,1
    __syncthreads();
    if (kg < 2) merge_partial(kg);           // wave 0 <- buf0, wave 1 <- buf1
    __syncthreads();
    if (kg == 1) store_partial(0);
    __syncthreads();
    if (kg == 0) {
        merge_partial(0);
        // ---- finalize: bf16 hi/lo split to [B,S,H] ----
        const float inv = 1.0f / l;
        const size_t obase = ((size_t)(b * S_LEN + s)) * HDIM + h * DHEAD;
#pragma unroll
        for (int d4 = 0; d4 < DHEAD / 4; ++d4) {
            unsigned short hh[4], ll[4];
#pragma unroll
            for (int j = 0; j < 4; ++j) {
                const float val = o[d4 * 4 + j] * inv;
                hh[j] = bf16_rn(val);
                ll[j] = bf16_rn(val - bf16_f(hh[j]));
            }
            *reinterpret_cast<ushort4*>(&Ohi[obase + d4 * 4]) =
                make_ushort4(hh[0], hh[1], hh[2], hh[3]);
            *reinterpret_cast<ushort4*>(&Olo[obase + d4 * 4]) =
                make_ushort4(ll[0], ll[1], ll[2], ll[3]);
        }
    }
}

// ---------------------------------------------------------------------------
// Pipeline: split x -> split+transpose weights -> fused QKV MFMA GEMM (z=3)
// -> fp32 key-split sparse attention (emits bf16 hi/lo) -> MFMA GEMM (+bias).
// Workspace (80 MB): QKV fp32 48MB | x hi/lo 16MB (reused as attn-out hi/lo)
//                    | 4 weights hi/lo transposed 16MB (contiguous).
// ---------------------------------------------------------------------------
extern "C" void kernel_launch(void* const* d_in, const int* in_sizes, int n_in,
                              void* d_out, int out_size, void* d_ws, size_t ws_size,
                              hipStream_t stream)
{
    const float* x      = (const float*)d_in[0];
    const float* q_w    = (const float*)d_in[1];
    const float* k_w    = (const float*)d_in[2];
    const float* v_w    = (const float*)d_in[3];
    const float* o_w    = (const float*)d_in[4];
    const float* o_b    = (const float*)d_in[5];
    const float* uscale = (const float*)d_in[6];
    float* out = (float*)d_out;

    const size_t MB = (size_t)1 << 20;
    char* ws = (char*)d_ws;
    float* Qb = (float*)(ws);                               // QKV contiguous
    unsigned short* Xhi = (unsigned short*)(ws + 48 * MB);  // also attn-out hi
    unsigned short* Xlo = (unsigned short*)(ws + 56 * MB);  // also attn-out lo
    unsigned short* Wqkv = (unsigned short*)(ws + 64 * MB); // q_h,q_l,k_h,k_l,v_h,v_l
    unsigned short* Wo_h = (unsigned short*)(ws + 76 * MB);
    unsigned short* Wo_l = (unsigned short*)(ws + 78 * MB);

    float* Kb = Qb + (size_t)MROWS * HDIM;
    float* Vb = Kb + (size_t)MROWS * HDIM;

    // prep
    split_kernel<<<dim3(MROWS * HDIM / 4 / 256), dim3(256), 0, stream>>>(
        x, Xhi, Xlo, MROWS * HDIM / 4);
    const dim3 wtg(HDIM / 32, HDIM / 32);
    wsplit_kernel<<<wtg, dim3(256), 0, stream>>>(q_w, Wqkv + 0 * 1048576, Wqkv + 1 * 1048576);
    wsplit_kernel<<<wtg, dim3(256), 0, stream>>>(k_w, Wqkv + 2 * 1048576, Wqkv + 3 * 1048576);
    wsplit_kernel<<<wtg, dim3(256), 0, stream>>>(v_w, Wqkv + 4 * 1048576, Wqkv + 5 * 1048576);
    wsplit_kernel<<<wtg, dim3(256), 0, stream>>>(o_w, Wo_h, Wo_l);

    // fused QKV projection: blockIdx.z in {0,1,2} -> Q,K,V
    const dim3 gg(HDIM / 128, MROWS / 128, 3);   // (8, 32, 3)
    gemm_mfma<<<gg, dim3(256), 0, stream>>>(Xhi, Xlo, Wqkv, Qb, nullptr, uscale, 0);

    // attention (reads Q/K/V, overwrites Xhi/Xlo with its own hi/lo output)
    attn_kernel<<<dim3(BATCH * NHEADS * (S_LEN / QR)), dim3(256), 0, stream>>>(
        Qb, Kb, Vb, Xhi, Xlo);

    // output projection + bias
    const dim3 go(HDIM / 128, MROWS / 128, 1);
    gemm_mfma<<<go, dim3(256), 0, stream>>>(Xhi, Xlo, Wo_h, out, o_b, nullptr, 1);
}

// Round 4
// 252.146 us; speedup vs baseline: 2.7423x; 2.7423x over previous
//
#include <hip/hip_runtime.h>
#include <math.h>

// Problem constants (fixed by reference)
#define S_LEN   2048
#define HDIM    1024
#define NHEADS  16
#define DHEAD   64
#define BATCH   2
#define MROWS   (BATCH * S_LEN)   // 4096
#define STRIDE  4
#define LOCAL   8
#define NSTRIDED (S_LEN / STRIDE)  // 512

typedef __attribute__((ext_vector_type(8))) short s16x8;   // 8 bf16 (4 VGPRs)
typedef __attribute__((ext_vector_type(4))) float f32x4;

// ---- fp32 -> bf16 round-to-nearest-even, and back --------------------------
__device__ __forceinline__ unsigned short bf16_rn(float x) {
    unsigned u = __float_as_uint(x);
    unsigned r = (u + 0x7FFFu + ((u >> 16) & 1u)) >> 16;
    return (unsigned short)r;
}
__device__ __forceinline__ float bf16_f(unsigned short h) {
    return __uint_as_float(((unsigned)h) << 16);
}
__device__ __forceinline__ unsigned pack2_bf16(float a, float b) {
    return (unsigned)bf16_rn(a) | ((unsigned)bf16_rn(b) << 16);
}

// ---- async global->LDS, 16B per lane (dest = wave base + lane*16) ----------
__device__ __forceinline__ void gll16(const void* g, void* l) {
    __builtin_amdgcn_global_load_lds(
        (const __attribute__((address_space(1))) void*)g,
        (__attribute__((address_space(3))) void*)l, 16, 0, 0);
}

// ---------------------------------------------------------------------------
// Prep 1: elementwise fp32 -> (bf16 hi, bf16 lo) split. 4 elems/thread.
// ---------------------------------------------------------------------------
__global__ __launch_bounds__(256)
void split_kernel(const float* __restrict__ src, unsigned short* __restrict__ hi,
                  unsigned short* __restrict__ lo, int n4)
{
    const int i = blockIdx.x * 256 + threadIdx.x;
    if (i >= n4) return;
    const float4 v = reinterpret_cast<const float4*>(src)[i];
    const float vv[4] = {v.x, v.y, v.z, v.w};
    unsigned short hh[4], ll[4];
#pragma unroll
    for (int j = 0; j < 4; j++) {
        hh[j] = bf16_rn(vv[j]);
        ll[j] = bf16_rn(vv[j] - bf16_f(hh[j]));
    }
    reinterpret_cast<ushort4*>(hi)[i] = make_ushort4(hh[0], hh[1], hh[2], hh[3]);
    reinterpret_cast<ushort4*>(lo)[i] = make_ushort4(ll[0], ll[1], ll[2], ll[3]);
}

// ---------------------------------------------------------------------------
// Prep 2: weight [K][N] fp32 -> transposed bf16 hi/lo [N][K], 32x32 LDS tiles.
// ---------------------------------------------------------------------------
__global__ __launch_bounds__(256)
void wsplit_kernel(const float* __restrict__ W,
                   unsigned short* __restrict__ hiT, unsigned short* __restrict__ loT)
{
    __shared__ unsigned short his[32][33];
    __shared__ unsigned short los[32][33];
    const int t  = threadIdx.x;
    const int kb = blockIdx.x * 32;
    const int nb = blockIdx.y * 32;
    {
        const int row = t >> 3;          // k within tile
        const int c4  = (t & 7) * 4;     // n within tile
        const float4 v = *reinterpret_cast<const float4*>(
            &W[(size_t)(kb + row) * HDIM + nb + c4]);
        const float vv[4] = {v.x, v.y, v.z, v.w};
#pragma unroll
        for (int j = 0; j < 4; j++) {
            const unsigned short h = bf16_rn(vv[j]);
            his[row][c4 + j] = h;
            los[row][c4 + j] = bf16_rn(vv[j] - bf16_f(h));
        }
    }
    __syncthreads();
    {
        const int n  = t >> 3;
        const int k4 = (t & 7) * 4;
        const ushort4 h = make_ushort4(his[k4][n], his[k4+1][n], his[k4+2][n], his[k4+3][n]);
        const ushort4 l = make_ushort4(los[k4][n], los[k4+1][n], los[k4+2][n], los[k4+3][n]);
        *reinterpret_cast<ushort4*>(&hiT[(size_t)(nb + n) * HDIM + kb + k4]) = h;
        *reinterpret_cast<ushort4*>(&loT[(size_t)(nb + n) * HDIM + kb + k4]) = l;
    }
}

// ---------------------------------------------------------------------------
// MFMA GEMM with 3-term bf16 split: C = Ahi@Whi + Ahi@Wlo + Alo@Whi.
// Tile 128x128, 4 waves (2x2), 4x4 frags/wave, BK=64, double-buffered LDS
// via global_load_lds with pre-swizzled source.
// mode 0 (gridDim.z==3): attention-prep epilogue, z picks Q/K/V target:
//   z=0: Q bf16 [b,h,s,d], scaled by sigmoid(*sig)/8
//   z=1: K bf16 [b,h,s,d] full + packed strided Kp [b,h,jj,d]
//   z=2: V bf16 transposed Vt [b,h,d,s] + packed transposed Vpt [b,h,d,jj]
// mode 1: fp32 flat [M][N] + bias.
// ---------------------------------------------------------------------------
__global__ __launch_bounds__(256)
void gemm_mfma(const unsigned short* __restrict__ Ahi, const unsigned short* __restrict__ Alo,
               const unsigned short* __restrict__ Wbase,
               float* __restrict__ C, const float* __restrict__ bias,
               const float* __restrict__ sig_ptr, int mode,
               unsigned short* __restrict__ Qf, unsigned short* __restrict__ Kf,
               unsigned short* __restrict__ Kp, unsigned short* __restrict__ Vt,
               unsigned short* __restrict__ Vpt)
{
    __shared__ unsigned short As[2][128 * 64];
    __shared__ unsigned short Bs[2][128 * 64];

    const int z = blockIdx.z;
    const unsigned short* __restrict__ WhiT = Wbase + (size_t)z * 2097152;
    const unsigned short* __restrict__ WloT = WhiT + 1048576;

    const int tid  = threadIdx.x;
    const int lane = tid & 63;
    const int w    = tid >> 6;
    const int wr   = w >> 1;
    const int wc   = w & 1;
    const int row_base = blockIdx.y * 128;
    const int col_base = blockIdx.x * 128;

    f32x4 acc[4][4] = {};

    auto stage = [&](int b, const unsigned short* Ap, const unsigned short* Bp, int k0) {
#pragma unroll
        for (int r = 0; r < 4; ++r) {
            const int c    = tid + r * 256;      // chunk id 0..1023
            const int row  = c >> 3;             // tile row 0..127
            const int c7   = c & 7;              // 16B chunk within 128B row
            const int goff = ((c7 * 16) ^ ((row & 7) << 4)) >> 1;  // bf16 elems
            gll16(Ap + (size_t)(row_base + row) * HDIM + k0 + goff, &As[b][c * 8]);
            gll16(Bp + (size_t)(col_base + row) * HDIM + k0 + goff, &Bs[b][c * 8]);
        }
    };

    auto compute = [&](int b) {
#pragma unroll
        for (int kk = 0; kk < 2; ++kk) {
            const int sofs = (kk * 64 + ((lane >> 4) << 4)) ^ ((lane & 7) << 4);
            s16x8 af[4], bfr[4];
#pragma unroll
            for (int mi = 0; mi < 4; ++mi) {
                const int row = wr * 64 + mi * 16 + (lane & 15);
                af[mi] = *reinterpret_cast<const s16x8*>(
                    reinterpret_cast<const char*>(&As[b][row * 64]) + sofs);
            }
#pragma unroll
            for (int ni = 0; ni < 4; ++ni) {
                const int row = wc * 64 + ni * 16 + (lane & 15);
                bfr[ni] = *reinterpret_cast<const s16x8*>(
                    reinterpret_cast<const char*>(&Bs[b][row * 64]) + sofs);
            }
#pragma unroll
            for (int mi = 0; mi < 4; ++mi)
#pragma unroll
                for (int ni = 0; ni < 4; ++ni)
                    acc[mi][ni] = __builtin_amdgcn_mfma_f32_16x16x32_bf16(
                        af[mi], bfr[ni], acc[mi][ni], 0, 0, 0);
        }
    };

    stage(0, Ahi, WhiT, 0);
    __syncthreads();
    int buf = 0;
#pragma unroll 1
    for (int kt = 0; kt < 48; ++kt) {
        if (kt + 1 < 48) {
            const int nx = kt + 1;
            const int v  = nx >> 4;
            const int k0 = (nx & 15) * 64;
            const unsigned short* Ap = (v == 2) ? Alo  : Ahi;
            const unsigned short* Bp = (v == 1) ? WloT : WhiT;
            stage(buf ^ 1, Ap, Bp, k0);
        }
        compute(buf);
        __syncthreads();
        buf ^= 1;
    }

    // ---- epilogue ----
    float scale = 1.0f;
    if (mode == 0 && z == 0) {
        const float u = *sig_ptr;
        scale = (1.0f / (1.0f + __expf(-u))) * 0.125f;  // sigmoid(phi)/sqrt(D)
    }
#pragma unroll
    for (int mi = 0; mi < 4; ++mi) {
#pragma unroll
        for (int ni = 0; ni < 4; ++ni) {
            const int gr0 = row_base + wr * 64 + mi * 16 + ((lane >> 4) << 2);
            const int gc  = col_base + wc * 64 + ni * 16 + (lane & 15);
            if (mode == 0) {
                const int h = gc >> 6, d = gc & 63;
                const int bb = gr0 >> 11;
                const int s0 = gr0 & (S_LEN - 1);       // multiple of 4
                const size_t bh = (size_t)(bb * NHEADS + h);
                if (z == 0) {
#pragma unroll
                    for (int r = 0; r < 4; ++r)
                        Qf[(bh * S_LEN + s0 + r) * DHEAD + d] =
                            bf16_rn(acc[mi][ni][r] * scale);
                } else if (z == 1) {
#pragma unroll
                    for (int r = 0; r < 4; ++r)
                        Kf[(bh * S_LEN + s0 + r) * DHEAD + d] =
                            bf16_rn(acc[mi][ni][r]);
                    Kp[(bh * NSTRIDED + (s0 >> 2)) * DHEAD + d] =
                        bf16_rn(acc[mi][ni][0]);
                } else {
                    ushort4 pv = make_ushort4(bf16_rn(acc[mi][ni][0]), bf16_rn(acc[mi][ni][1]),
                                              bf16_rn(acc[mi][ni][2]), bf16_rn(acc[mi][ni][3]));
                    *reinterpret_cast<ushort4*>(&Vt[(bh * DHEAD + d) * S_LEN + s0]) = pv;
                    Vpt[(bh * DHEAD + d) * NSTRIDED + (s0 >> 2)] = pv.x;
                }
            } else {
                const float bv = bias[gc];
#pragma unroll
                for (int r = 0; r < 4; ++r)
                    C[(size_t)(gr0 + r) * HDIM + gc] = acc[mi][ni][r] + bv;
            }
        }
    }
}

// ---------------------------------------------------------------------------
// MFMA sparse ("strided") flash attention, bf16 inputs, fp32 softmax.
// Block = 4 independent waves; wave owns 16 q-rows. Grid = 2*16*32 = 1024.
// Per 32-key chunk: swapped QK^T (D[key,q], q=lane&15), lane-local online
// softmax, P -> bf16 via per-wave LDS scratch [q][key], swapped PV
// (D[d,q]) so rescale/divide/store are all lane-local. 16 strided chunks
// (packed Kp/Vpt) + 1 masked band chunk (window [r0-8, r0+24) from Kf/Vt).
// No __syncthreads anywhere. Output: bf16 hi/lo for the 3-term o-proj.
// ---------------------------------------------------------------------------
__global__ __launch_bounds__(256)
void attn_mfma(const unsigned short* __restrict__ Qf, const unsigned short* __restrict__ Kf,
               const unsigned short* __restrict__ Kp, const unsigned short* __restrict__ Vt,
               const unsigned short* __restrict__ Vpt,
               unsigned short* __restrict__ Ohi, unsigned short* __restrict__ Olo)
{
    __shared__ unsigned short P[4][16][40];   // per-wave [q][key] scratch, pad->80B rows

    const int tid = threadIdx.x;
    const int L = tid & 63, w = tid >> 6;
    const int c = L & 15, g = L >> 4;
    const int bx = blockIdx.x;
    const int qt = bx & 31;
    const int h  = (bx >> 5) & 15;
    const int b  = bx >> 9;
    const int r0 = qt * 64 + w * 16;
    const size_t bh = (size_t)(b * NHEADS + h);

    const unsigned short* __restrict__ Qb  = Qf  + bh * S_LEN * DHEAD;
    const unsigned short* __restrict__ Kfb = Kf  + bh * S_LEN * DHEAD;
    const unsigned short* __restrict__ Kpb = Kp  + bh * NSTRIDED * DHEAD;
    const unsigned short* __restrict__ Vtb = Vt  + bh * DHEAD * S_LEN;
    const unsigned short* __restrict__ Vpb = Vpt + bh * DHEAD * NSTRIDED;

    // Q B-fragments (held for the whole kernel): q-row = r0+c, d-slices 0/1
    s16x8 qf0 = *reinterpret_cast<const s16x8*>(&Qb[(r0 + c) * DHEAD + 8 * g]);
    s16x8 qf1 = *reinterpret_cast<const s16x8*>(&Qb[(r0 + c) * DHEAD + 32 + 8 * g]);

    f32x4 acc[4] = {};            // out[d = dt*16 + 4g + reg][q = c]
    float m = -1e30f, lsum = 0.f; // per-lane; q = c (replicated across g)

    char* const Pb = (char*)&P[w][c][0];

    auto chunk = [&](const s16x8 kfr[2][2], const s16x8 vfr[4], bool band, int j0) {
        // ---- QK^T (swapped): D[key, q] ----
        f32x4 sc0 = {}, sc1 = {};
        sc0 = __builtin_amdgcn_mfma_f32_16x16x32_bf16(kfr[0][0], qf0, sc0, 0, 0, 0);
        sc0 = __builtin_amdgcn_mfma_f32_16x16x32_bf16(kfr[0][1], qf1, sc0, 0, 0, 0);
        sc1 = __builtin_amdgcn_mfma_f32_16x16x32_bf16(kfr[1][0], qf0, sc1, 0, 0, 0);
        sc1 = __builtin_amdgcn_mfma_f32_16x16x32_bf16(kfr[1][1], qf1, sc1, 0, 0, 0);

        if (band) {
            const int i = r0 + c;
#pragma unroll
            for (int r = 0; r < 4; ++r) {
                const int j = j0 + 4 * g + r;
                const bool ok = (j >= 0) && (j < S_LEN) && ((j & 3) != 0) &&
                                (j >= i - LOCAL) && (j <= i + LOCAL);
                if (!ok) sc0[r] = -1e30f;
            }
#pragma unroll
            for (int r = 0; r < 4; ++r) {
                const int j = j0 + 16 + 4 * g + r;
                const bool ok = (j >= 0) && (j < S_LEN) && ((j & 3) != 0) &&
                                (j >= i - LOCAL) && (j <= i + LOCAL);
                if (!ok) sc1[r] = -1e30f;
            }
        }

        // ---- online softmax (per q = c; lanes of same c track identical m) ----
        float pmax = fmaxf(fmaxf(fmaxf(sc0[0], sc0[1]), fmaxf(sc0[2], sc0[3])),
                           fmaxf(fmaxf(sc1[0], sc1[1]), fmaxf(sc1[2], sc1[3])));
        pmax = fmaxf(pmax, __shfl_xor(pmax, 16));
        pmax = fmaxf(pmax, __shfl_xor(pmax, 32));
        if (__any(pmax > m + 8.0f)) {          // defer-max: rare, wave-uniform
            const float mn = fmaxf(m, pmax);
            const float f  = __expf(m - mn);
            lsum *= f;
#pragma unroll
            for (int dt = 0; dt < 4; ++dt)
#pragma unroll
                for (int r = 0; r < 4; ++r) acc[dt][r] *= f;
            m = mn;
        }
        float p[8];
#pragma unroll
        for (int r = 0; r < 4; ++r) p[r]     = __expf(sc0[r] - m);
#pragma unroll
        for (int r = 0; r < 4; ++r) p[4 + r] = __expf(sc1[r] - m);
        lsum += ((p[0] + p[1]) + (p[2] + p[3])) + ((p[4] + p[5]) + (p[6] + p[7]));

        // ---- P -> bf16 via per-wave LDS [q][key] (same-wave, no barrier) ----
        *reinterpret_cast<uint2*>(Pb + 8 * g) =
            make_uint2(pack2_bf16(p[0], p[1]), pack2_bf16(p[2], p[3]));
        *reinterpret_cast<uint2*>(Pb + 32 + 8 * g) =
            make_uint2(pack2_bf16(p[4], p[5]), pack2_bf16(p[6], p[7]));
        const s16x8 pf = *reinterpret_cast<const s16x8*>(Pb + 16 * g);

        // ---- PV (swapped): D[d, q] ----
#pragma unroll
        for (int dt = 0; dt < 4; ++dt)
            acc[dt] = __builtin_amdgcn_mfma_f32_16x16x32_bf16(vfr[dt], pf, acc[dt], 0, 0, 0);
    };

    // ---- 16 strided chunks (512 packed keys) ----
#pragma unroll 2
    for (int kt = 0; kt < 16; ++kt) {
        const int jj0 = kt * 32;
        s16x8 kfr[2][2], vfr[4];
#pragma unroll
        for (int half = 0; half < 2; ++half)
#pragma unroll
            for (int sl = 0; sl < 2; ++sl)
                kfr[half][sl] = *reinterpret_cast<const s16x8*>(
                    &Kpb[(jj0 + half * 16 + c) * DHEAD + sl * 32 + 8 * g]);
#pragma unroll
        for (int dt = 0; dt < 4; ++dt)
            vfr[dt] = *reinterpret_cast<const s16x8*>(
                &Vpb[(dt * 16 + c) * NSTRIDED + jj0 + 8 * g]);
        chunk(kfr, vfr, false, 0);
    }

    // ---- 1 masked band chunk: keys j in [r0-8, r0+24) ----
    {
        const int j0 = r0 - LOCAL;
        s16x8 kfr[2][2], vfr[4];
#pragma unroll
        for (int half = 0; half < 2; ++half) {
            int j = j0 + half * 16 + c;
            j = min(max(j, 0), S_LEN - 1);
#pragma unroll
            for (int sl = 0; sl < 2; ++sl)
                kfr[half][sl] = *reinterpret_cast<const s16x8*>(
                    &Kfb[j * DHEAD + sl * 32 + 8 * g]);
        }
        int js = j0 + 8 * g;
        js = min(max(js, 0), S_LEN - 8);
#pragma unroll
        for (int dt = 0; dt < 4; ++dt)
            vfr[dt] = *reinterpret_cast<const s16x8*>(
                &Vtb[(dt * 16 + c) * S_LEN + js]);
        chunk(kfr, vfr, true, j0);
    }

    // ---- finalize (all lane-local in q = c) ----
    lsum += __shfl_xor(lsum, 16);
    lsum += __shfl_xor(lsum, 32);
    const float inv = 1.0f / lsum;
    const int s = r0 + c;
    const size_t ob = ((size_t)(b * S_LEN + s)) * HDIM + h * DHEAD;
#pragma unroll
    for (int dt = 0; dt < 4; ++dt) {
        ushort4 hv, lv;
        float vals[4];
#pragma unroll
        for (int r = 0; r < 4; ++r) vals[r] = acc[dt][r] * inv;
        hv = make_ushort4(bf16_rn(vals[0]), bf16_rn(vals[1]),
                          bf16_rn(vals[2]), bf16_rn(vals[3]));
        lv = make_ushort4(bf16_rn(vals[0] - bf16_f(hv.x)), bf16_rn(vals[1] - bf16_f(hv.y)),
                          bf16_rn(vals[2] - bf16_f(hv.z)), bf16_rn(vals[3] - bf16_f(hv.w)));
        *reinterpret_cast<ushort4*>(&Ohi[ob + dt * 16 + 4 * g]) = hv;
        *reinterpret_cast<ushort4*>(&Olo[ob + dt * 16 + 4 * g]) = lv;
    }
}

// ---------------------------------------------------------------------------
// Pipeline: split x -> split+transpose weights -> fused QKV MFMA GEMM (z=3,
// bf16 attention-layout epilogue) -> MFMA sparse attention (bf16 hi/lo out)
// -> MFMA o-proj GEMM (+bias).
// Workspace (60 MB): Xhi 0-8 | Xlo 8-16 | Wqkv 16-28 | Wo 28-32 |
//                    Qf 32-40 | Kf 40-48 | Kp 48-50 | Vt 50-58 | Vpt 58-60.
// Xhi/Xlo are reused as attention-output hi/lo (consumed before overwrite).
// ---------------------------------------------------------------------------
extern "C" void kernel_launch(void* const* d_in, const int* in_sizes, int n_in,
                              void* d_out, int out_size, void* d_ws, size_t ws_size,
                              hipStream_t stream)
{
    const float* x      = (const float*)d_in[0];
    const float* q_w    = (const float*)d_in[1];
    const float* k_w    = (const float*)d_in[2];
    const float* v_w    = (const float*)d_in[3];
    const float* o_w    = (const float*)d_in[4];
    const float* o_b    = (const float*)d_in[5];
    const float* uscale = (const float*)d_in[6];
    float* out = (float*)d_out;

    const size_t MB = (size_t)1 << 20;
    char* ws = (char*)d_ws;
    unsigned short* Xhi  = (unsigned short*)(ws);            // also attn-out hi
    unsigned short* Xlo  = (unsigned short*)(ws + 8 * MB);   // also attn-out lo
    unsigned short* Wqkv = (unsigned short*)(ws + 16 * MB);  // 6 x 2MB (hi/lo x3)
    unsigned short* Wo_h = (unsigned short*)(ws + 28 * MB);  // +Wo_l contiguous
    unsigned short* Qf   = (unsigned short*)(ws + 32 * MB);
    unsigned short* Kf   = (unsigned short*)(ws + 40 * MB);
    unsigned short* Kp   = (unsigned short*)(ws + 48 * MB);
    unsigned short* Vt   = (unsigned short*)(ws + 50 * MB);
    unsigned short* Vpt  = (unsigned short*)(ws + 58 * MB);

    // prep
    split_kernel<<<dim3(MROWS * HDIM / 4 / 256), dim3(256), 0, stream>>>(
        x, Xhi, Xlo, MROWS * HDIM / 4);
    const dim3 wtg(HDIM / 32, HDIM / 32);
    wsplit_kernel<<<wtg, dim3(256), 0, stream>>>(q_w, Wqkv + 0 * 1048576, Wqkv + 1 * 1048576);
    wsplit_kernel<<<wtg, dim3(256), 0, stream>>>(k_w, Wqkv + 2 * 1048576, Wqkv + 3 * 1048576);
    wsplit_kernel<<<wtg, dim3(256), 0, stream>>>(v_w, Wqkv + 4 * 1048576, Wqkv + 5 * 1048576);
    wsplit_kernel<<<wtg, dim3(256), 0, stream>>>(o_w, Wo_h, Wo_h + 1048576);

    // fused QKV projection: z in {0,1,2} -> Q / K(+Kp) / Vt(+Vpt), bf16 out
    const dim3 gg(HDIM / 128, MROWS / 128, 3);
    gemm_mfma<<<gg, dim3(256), 0, stream>>>(Xhi, Xlo, Wqkv, nullptr, nullptr,
                                            uscale, 0, Qf, Kf, Kp, Vt, Vpt);

    // MFMA sparse attention (overwrites Xhi/Xlo with attn-out hi/lo)
    attn_mfma<<<dim3(BATCH * NHEADS * (S_LEN / 64)), dim3(256), 0, stream>>>(
        Qf, Kf, Kp, Vt, Vpt, Xhi, Xlo);

    // output projection + bias (3-term split, fp32 out)
    const dim3 go(HDIM / 128, MROWS / 128, 1);
    gemm_mfma<<<go, dim3(256), 0, stream>>>(Xhi, Xlo, Wo_h, out, o_b,
                                            nullptr, 1, nullptr, nullptr,
                                            nullptr, nullptr, nullptr);
}

// Round 5
// 143.603 us; speedup vs baseline: 4.8151x; 1.7559x over previous
//
#include <hip/hip_runtime.h>
#include <math.h>

// Problem constants (fixed by reference)
#define S_LEN   2048
#define HDIM    1024
#define NHEADS  16
#define DHEAD   64
#define BATCH   2
#define MROWS   (BATCH * S_LEN)   // 4096
#define STRIDE  4
#define LOCAL   8
#define NSTRIDED (S_LEN / STRIDE)  // 512

typedef __attribute__((ext_vector_type(8))) _Float16 f16x8;  // 8 fp16 (4 VGPRs)
typedef __attribute__((ext_vector_type(4))) float f32x4;

// ---- fp32 -> fp16 (RN) bit helpers -----------------------------------------
__device__ __forceinline__ unsigned short f16b(float x) {
    _Float16 h = (_Float16)x;
    unsigned short u;
    __builtin_memcpy(&u, &h, 2);
    return u;
}
__device__ __forceinline__ unsigned pack2_f16(float a, float b) {
    return (unsigned)f16b(a) | ((unsigned)f16b(b) << 16);
}

// ---- async global->LDS, 16B per lane (dest = wave base + lane*16) ----------
__device__ __forceinline__ void gll16(const void* g, void* l) {
    __builtin_amdgcn_global_load_lds(
        (const __attribute__((address_space(1))) void*)g,
        (__attribute__((address_space(3))) void*)l, 16, 0, 0);
}

// ---------------------------------------------------------------------------
// Prep 1: x fp32 -> fp16 bits, 4 elems/thread.
// ---------------------------------------------------------------------------
__global__ __launch_bounds__(256)
void xcvt(const float* __restrict__ src, unsigned short* __restrict__ dst, int n4)
{
    const int i = blockIdx.x * 256 + threadIdx.x;
    if (i >= n4) return;
    const float4 v = reinterpret_cast<const float4*>(src)[i];
    reinterpret_cast<ushort4*>(dst)[i] =
        make_ushort4(f16b(v.x), f16b(v.y), f16b(v.z), f16b(v.w));
}

// ---------------------------------------------------------------------------
// Prep 2: weights [K][N] fp32 -> transposed fp16 [N][K]; z picks which of the
// 4 weights; outputs packed contiguously at dst + z*HDIM*HDIM.
// ---------------------------------------------------------------------------
__global__ __launch_bounds__(256)
void wcvt(const float* __restrict__ W0, const float* __restrict__ W1,
          const float* __restrict__ W2, const float* __restrict__ W3,
          unsigned short* __restrict__ dst)
{
    __shared__ unsigned short tile[32][33];
    const int z = blockIdx.z;
    const float* __restrict__ W = (z == 0) ? W0 : (z == 1) ? W1 : (z == 2) ? W2 : W3;
    unsigned short* __restrict__ out = dst + (size_t)z * HDIM * HDIM;
    const int t  = threadIdx.x;
    const int kb = blockIdx.x * 32;
    const int nb = blockIdx.y * 32;
    {
        const int row = t >> 3;          // k within tile
        const int c4  = (t & 7) * 4;     // n within tile
        const float4 v = *reinterpret_cast<const float4*>(
            &W[(size_t)(kb + row) * HDIM + nb + c4]);
        tile[row][c4 + 0] = f16b(v.x);
        tile[row][c4 + 1] = f16b(v.y);
        tile[row][c4 + 2] = f16b(v.z);
        tile[row][c4 + 3] = f16b(v.w);
    }
    __syncthreads();
    {
        const int n  = t >> 3;
        const int k4 = (t & 7) * 4;
        *reinterpret_cast<ushort4*>(&out[(size_t)(nb + n) * HDIM + kb + k4]) =
            make_ushort4(tile[k4][n], tile[k4+1][n], tile[k4+2][n], tile[k4+3][n]);
    }
}

// ---------------------------------------------------------------------------
// fp16 MFMA GEMM, single-term (fp32 accumulate): C = A @ W.
// A: [4096][1024] fp16 bits. W TRANSPOSED [N][K] fp16, z*HDIM*HDIM offset.
// Tile 64x64, BK=64, 16 K-iters, 4 waves (2x2), 2x2 frags/wave.
// LDS 32 KB double-buffered (5 blocks/CU cap); global_load_lds with
// pre-swizzled source; per-iter: stage-next -> compute -> one barrier.
// mode 0 (gridDim.z==3): attention-layout epilogue (z=0 Q scaled, z=1 K+Kp,
// z=2 Vt+Vpt). mode 1: fp32 flat [M][N] + bias.
// ---------------------------------------------------------------------------
__global__ __launch_bounds__(256)
void gemm_f16(const unsigned short* __restrict__ A,
              const unsigned short* __restrict__ Wbase,
              float* __restrict__ C, const float* __restrict__ bias,
              const float* __restrict__ sig_ptr, int mode,
              unsigned short* __restrict__ Qf, unsigned short* __restrict__ Kf,
              unsigned short* __restrict__ Kp, unsigned short* __restrict__ Vt,
              unsigned short* __restrict__ Vpt)
{
    __shared__ unsigned short As[2][64 * 64];
    __shared__ unsigned short Bs[2][64 * 64];

    const int z = blockIdx.z;
    const unsigned short* __restrict__ WT = Wbase + (size_t)z * HDIM * HDIM;

    const int tid  = threadIdx.x;
    const int lane = tid & 63;
    const int w    = tid >> 6;
    const int wr   = w >> 1;      // wave row: 32 rows
    const int wc   = w & 1;       // wave col: 32 cols
    const int row_base = blockIdx.y * 64;
    const int col_base = blockIdx.x * 64;

    f32x4 acc[2][2] = {};

    // stage 64x64 A-tile + 64x64 B-tile; LDS dest linear in chunk id,
    // global source pre-swizzled (row&7 XOR on the 16B slot).
    auto stage = [&](int b, int k0) {
#pragma unroll
        for (int r = 0; r < 2; ++r) {
            const int c    = tid + r * 256;      // chunk 0..511
            const int row  = c >> 3;             // tile row 0..63
            const int c7   = c & 7;              // 16B chunk in 128B row
            const int goff = ((c7 * 16) ^ ((row & 7) << 4)) >> 1;  // f16 elems
            gll16(A  + (size_t)(row_base + row) * HDIM + k0 + goff, &As[b][c * 8]);
            gll16(WT + (size_t)(col_base + row) * HDIM + k0 + goff, &Bs[b][c * 8]);
        }
    };

    auto compute = [&](int b) {
#pragma unroll
        for (int kk = 0; kk < 2; ++kk) {
            const int sofs = (kk * 64 + ((lane >> 4) << 4)) ^ ((lane & 7) << 4);
            f16x8 af[2], bfr[2];
#pragma unroll
            for (int mi = 0; mi < 2; ++mi) {
                const int row = wr * 32 + mi * 16 + (lane & 15);
                af[mi] = *reinterpret_cast<const f16x8*>(
                    reinterpret_cast<const char*>(&As[b][row * 64]) + sofs);
            }
#pragma unroll
            for (int ni = 0; ni < 2; ++ni) {
                const int row = wc * 32 + ni * 16 + (lane & 15);
                bfr[ni] = *reinterpret_cast<const f16x8*>(
                    reinterpret_cast<const char*>(&Bs[b][row * 64]) + sofs);
            }
#pragma unroll
            for (int mi = 0; mi < 2; ++mi)
#pragma unroll
                for (int ni = 0; ni < 2; ++ni)
                    acc[mi][ni] = __builtin_amdgcn_mfma_f32_16x16x32_f16(
                        af[mi], bfr[ni], acc[mi][ni], 0, 0, 0);
        }
    };

    stage(0, 0);
    __syncthreads();
    int buf = 0;
#pragma unroll 1
    for (int kt = 0; kt < 16; ++kt) {
        if (kt + 1 < 16) stage(buf ^ 1, (kt + 1) * 64);
        compute(buf);
        __syncthreads();
        buf ^= 1;
    }

    // ---- epilogue ----
    float scale = 1.0f;
    if (mode == 0 && z == 0) {
        const float u = *sig_ptr;
        scale = (1.0f / (1.0f + __expf(-u))) * 0.125f;  // sigmoid(phi)/sqrt(D)
    }
#pragma unroll
    for (int mi = 0; mi < 2; ++mi) {
#pragma unroll
        for (int ni = 0; ni < 2; ++ni) {
            const int gr0 = row_base + wr * 32 + mi * 16 + ((lane >> 4) << 2);
            const int gc  = col_base + wc * 32 + ni * 16 + (lane & 15);
            if (mode == 0) {
                const int h = gc >> 6, d = gc & 63;
                const int bb = gr0 >> 11;
                const int s0 = gr0 & (S_LEN - 1);       // multiple of 4
                const size_t bh = (size_t)(bb * NHEADS + h);
                if (z == 0) {
#pragma unroll
                    for (int r = 0; r < 4; ++r)
                        Qf[(bh * S_LEN + s0 + r) * DHEAD + d] =
                            f16b(acc[mi][ni][r] * scale);
                } else if (z == 1) {
#pragma unroll
                    for (int r = 0; r < 4; ++r)
                        Kf[(bh * S_LEN + s0 + r) * DHEAD + d] = f16b(acc[mi][ni][r]);
                    Kp[(bh * NSTRIDED + (s0 >> 2)) * DHEAD + d] = f16b(acc[mi][ni][0]);
                } else {
                    ushort4 pv = make_ushort4(f16b(acc[mi][ni][0]), f16b(acc[mi][ni][1]),
                                              f16b(acc[mi][ni][2]), f16b(acc[mi][ni][3]));
                    *reinterpret_cast<ushort4*>(&Vt[(bh * DHEAD + d) * S_LEN + s0]) = pv;
                    Vpt[(bh * DHEAD + d) * NSTRIDED + (s0 >> 2)] = pv.x;
                }
            } else {
                const float bv = bias[gc];
#pragma unroll
                for (int r = 0; r < 4; ++r)
                    C[(size_t)(gr0 + r) * HDIM + gc] = acc[mi][ni][r] + bv;
            }
        }
    }
}

// ---------------------------------------------------------------------------
// MFMA sparse ("strided") flash attention, fp16 inputs, fp32 softmax.
// Block = 4 independent waves; wave owns 16 q-rows. Grid = 2*16*32 = 1024.
// Per 32-key chunk: swapped QK^T (D[key,q], q=lane&15), lane-local online
// softmax, P -> fp16 via per-wave LDS scratch [q][key], swapped PV (D[d,q]).
// 16 strided chunks (packed Kp/Vpt) + 1 masked band chunk ([r0-8, r0+24)).
// No __syncthreads. Output: fp16 [B,S,H] (feeds single-term o-proj).
// ---------------------------------------------------------------------------
__global__ __launch_bounds__(256)
void attn_mfma(const unsigned short* __restrict__ Qf, const unsigned short* __restrict__ Kf,
               const unsigned short* __restrict__ Kp, const unsigned short* __restrict__ Vt,
               const unsigned short* __restrict__ Vpt,
               unsigned short* __restrict__ Of)
{
    __shared__ unsigned short P[4][16][40];   // per-wave [q][key] scratch

    const int tid = threadIdx.x;
    const int L = tid & 63, w = tid >> 6;
    const int c = L & 15, g = L >> 4;
    const int bx = blockIdx.x;
    const int qt = bx & 31;
    const int h  = (bx >> 5) & 15;
    const int b  = bx >> 9;
    const int r0 = qt * 64 + w * 16;
    const size_t bh = (size_t)(b * NHEADS + h);

    const unsigned short* __restrict__ Qb  = Qf  + bh * S_LEN * DHEAD;
    const unsigned short* __restrict__ Kfb = Kf  + bh * S_LEN * DHEAD;
    const unsigned short* __restrict__ Kpb = Kp  + bh * NSTRIDED * DHEAD;
    const unsigned short* __restrict__ Vtb = Vt  + bh * DHEAD * S_LEN;
    const unsigned short* __restrict__ Vpb = Vpt + bh * DHEAD * NSTRIDED;

    // Q B-fragments (held for the whole kernel): q-row = r0+c, d-slices 0/1
    const f16x8 qf0 = *reinterpret_cast<const f16x8*>(&Qb[(r0 + c) * DHEAD + 8 * g]);
    const f16x8 qf1 = *reinterpret_cast<const f16x8*>(&Qb[(r0 + c) * DHEAD + 32 + 8 * g]);

    f32x4 acc[4] = {};            // out[d = dt*16 + 4g + reg][q = c]
    float m = -1e30f, lsum = 0.f;

    char* const Pb = (char*)&P[w][c][0];

    auto chunk = [&](const f16x8 kfr[2][2], const f16x8 vfr[4], bool band, int j0) {
        // ---- QK^T (swapped): D[key, q] ----
        f32x4 sc0 = {}, sc1 = {};
        sc0 = __builtin_amdgcn_mfma_f32_16x16x32_f16(kfr[0][0], qf0, sc0, 0, 0, 0);
        sc0 = __builtin_amdgcn_mfma_f32_16x16x32_f16(kfr[0][1], qf1, sc0, 0, 0, 0);
        sc1 = __builtin_amdgcn_mfma_f32_16x16x32_f16(kfr[1][0], qf0, sc1, 0, 0, 0);
        sc1 = __builtin_amdgcn_mfma_f32_16x16x32_f16(kfr[1][1], qf1, sc1, 0, 0, 0);

        if (band) {
            const int i = r0 + c;
#pragma unroll
            for (int r = 0; r < 4; ++r) {
                const int j = j0 + 4 * g + r;
                const bool ok = (j >= 0) && (j < S_LEN) && ((j & 3) != 0) &&
                                (j >= i - LOCAL) && (j <= i + LOCAL);
                if (!ok) sc0[r] = -1e30f;
            }
#pragma unroll
            for (int r = 0; r < 4; ++r) {
                const int j = j0 + 16 + 4 * g + r;
                const bool ok = (j >= 0) && (j < S_LEN) && ((j & 3) != 0) &&
                                (j >= i - LOCAL) && (j <= i + LOCAL);
                if (!ok) sc1[r] = -1e30f;
            }
        }

        // ---- online softmax (per q = c) ----
        float pmax = fmaxf(fmaxf(fmaxf(sc0[0], sc0[1]), fmaxf(sc0[2], sc0[3])),
                           fmaxf(fmaxf(sc1[0], sc1[1]), fmaxf(sc1[2], sc1[3])));
        pmax = fmaxf(pmax, __shfl_xor(pmax, 16));
        pmax = fmaxf(pmax, __shfl_xor(pmax, 32));
        if (__any(pmax > m + 8.0f)) {          // defer-max: rare, wave-uniform
            const float mn = fmaxf(m, pmax);
            const float f  = __expf(m - mn);
            lsum *= f;
#pragma unroll
            for (int dt = 0; dt < 4; ++dt)
#pragma unroll
                for (int r = 0; r < 4; ++r) acc[dt][r] *= f;
            m = mn;
        }
        float p[8];
#pragma unroll
        for (int r = 0; r < 4; ++r) p[r]     = __expf(sc0[r] - m);
#pragma unroll
        for (int r = 0; r < 4; ++r) p[4 + r] = __expf(sc1[r] - m);
        lsum += ((p[0] + p[1]) + (p[2] + p[3])) + ((p[4] + p[5]) + (p[6] + p[7]));

        // ---- P -> fp16 via per-wave LDS [q][key] (same-wave, no barrier) ----
        *reinterpret_cast<uint2*>(Pb + 8 * g) =
            make_uint2(pack2_f16(p[0], p[1]), pack2_f16(p[2], p[3]));
        *reinterpret_cast<uint2*>(Pb + 32 + 8 * g) =
            make_uint2(pack2_f16(p[4], p[5]), pack2_f16(p[6], p[7]));
        const f16x8 pf = *reinterpret_cast<const f16x8*>(Pb + 16 * g);

        // ---- PV (swapped): D[d, q] ----
#pragma unroll
        for (int dt = 0; dt < 4; ++dt)
            acc[dt] = __builtin_amdgcn_mfma_f32_16x16x32_f16(vfr[dt], pf, acc[dt], 0, 0, 0);
    };

    // ---- 16 strided chunks (512 packed keys) ----
#pragma unroll 2
    for (int kt = 0; kt < 16; ++kt) {
        const int jj0 = kt * 32;
        f16x8 kfr[2][2], vfr[4];
#pragma unroll
        for (int half = 0; half < 2; ++half)
#pragma unroll
            for (int sl = 0; sl < 2; ++sl)
                kfr[half][sl] = *reinterpret_cast<const f16x8*>(
                    &Kpb[(jj0 + half * 16 + c) * DHEAD + sl * 32 + 8 * g]);
#pragma unroll
        for (int dt = 0; dt < 4; ++dt)
            vfr[dt] = *reinterpret_cast<const f16x8*>(
                &Vpb[(dt * 16 + c) * NSTRIDED + jj0 + 8 * g]);
        chunk(kfr, vfr, false, 0);
    }

    // ---- 1 masked band chunk: keys j in [r0-8, r0+24) ----
    {
        const int j0 = r0 - LOCAL;
        f16x8 kfr[2][2], vfr[4];
#pragma unroll
        for (int half = 0; half < 2; ++half) {
            int j = j0 + half * 16 + c;
            j = min(max(j, 0), S_LEN - 1);
#pragma unroll
            for (int sl = 0; sl < 2; ++sl)
                kfr[half][sl] = *reinterpret_cast<const f16x8*>(
                    &Kfb[j * DHEAD + sl * 32 + 8 * g]);
        }
        int js = j0 + 8 * g;
        js = min(max(js, 0), S_LEN - 8);
#pragma unroll
        for (int dt = 0; dt < 4; ++dt)
            vfr[dt] = *reinterpret_cast<const f16x8*>(
                &Vtb[(dt * 16 + c) * S_LEN + js]);
        chunk(kfr, vfr, true, j0);
    }

    // ---- finalize (lane-local in q = c) ----
    lsum += __shfl_xor(lsum, 16);
    lsum += __shfl_xor(lsum, 32);
    const float inv = 1.0f / lsum;
    const int s = r0 + c;
    const size_t ob = ((size_t)(b * S_LEN + s)) * HDIM + h * DHEAD;
#pragma unroll
    for (int dt = 0; dt < 4; ++dt) {
        ushort4 hv = make_ushort4(f16b(acc[dt][0] * inv), f16b(acc[dt][1] * inv),
                                  f16b(acc[dt][2] * inv), f16b(acc[dt][3] * inv));
        *reinterpret_cast<ushort4*>(&Of[ob + dt * 16 + 4 * g]) = hv;
    }
}

// ---------------------------------------------------------------------------
// Pipeline: x->fp16, W->fp16 transposed (batched z=4) -> fused QKV fp16 GEMM
// (z=3, attention layouts) -> MFMA sparse attention (fp16 out) -> o-proj
// fp16 GEMM (+bias, fp32 out).
// Workspace (52 MB): Xf 0-8 | Wall 8-16 (Wq,Wk,Wv,Wo T fp16) | Qf 16-24 |
//                    Kf 24-32 | Kp 32-34 | Vt 34-42 | Vpt 42-44 | Of 44-52.
// ---------------------------------------------------------------------------
extern "C" void kernel_launch(void* const* d_in, const int* in_sizes, int n_in,
                              void* d_out, int out_size, void* d_ws, size_t ws_size,
                              hipStream_t stream)
{
    const float* x      = (const float*)d_in[0];
    const float* q_w    = (const float*)d_in[1];
    const float* k_w    = (const float*)d_in[2];
    const float* v_w    = (const float*)d_in[3];
    const float* o_w    = (const float*)d_in[4];
    const float* o_b    = (const float*)d_in[5];
    const float* uscale = (const float*)d_in[6];
    float* out = (float*)d_out;

    const size_t MB = (size_t)1 << 20;
    char* ws = (char*)d_ws;
    unsigned short* Xf   = (unsigned short*)(ws);
    unsigned short* Wall = (unsigned short*)(ws + 8 * MB);   // 4 x 2MB fp16 [N][K]
    unsigned short* Qf   = (unsigned short*)(ws + 16 * MB);
    unsigned short* Kf   = (unsigned short*)(ws + 24 * MB);
    unsigned short* Kp   = (unsigned short*)(ws + 32 * MB);
    unsigned short* Vt   = (unsigned short*)(ws + 34 * MB);
    unsigned short* Vpt  = (unsigned short*)(ws + 42 * MB);
    unsigned short* Of   = (unsigned short*)(ws + 44 * MB);

    // prep: x and weights to fp16 (weights transposed), one launch each
    xcvt<<<dim3(MROWS * HDIM / 4 / 256), dim3(256), 0, stream>>>(
        x, Xf, MROWS * HDIM / 4);
    wcvt<<<dim3(HDIM / 32, HDIM / 32, 4), dim3(256), 0, stream>>>(
        q_w, k_w, v_w, o_w, Wall);

    // fused QKV projection: z in {0,1,2} -> Q / K(+Kp) / Vt(+Vpt), fp16 out
    const dim3 gg(HDIM / 64, MROWS / 64, 3);   // (16, 64, 3) = 3072 blocks
    gemm_f16<<<gg, dim3(256), 0, stream>>>(Xf, Wall, nullptr, nullptr,
                                           uscale, 0, Qf, Kf, Kp, Vt, Vpt);

    // MFMA sparse attention -> Of (fp16 [B,S,H])
    attn_mfma<<<dim3(BATCH * NHEADS * (S_LEN / 64)), dim3(256), 0, stream>>>(
        Qf, Kf, Kp, Vt, Vpt, Of);

    // output projection + bias (single-term fp16, fp32 out)
    const dim3 go(HDIM / 64, MROWS / 64, 1);   // (16, 64) = 1024 blocks
    gemm_f16<<<go, dim3(256), 0, stream>>>(Of, Wall + 3 * (size_t)HDIM * HDIM,
                                           out, o_b, nullptr, 1,
                                           nullptr, nullptr, nullptr, nullptr, nullptr);
}